// Round 1
// baseline (609.317 us; speedup 1.0000x reference)
//
#include <hip/hip_runtime.h>

typedef unsigned short ushort_t;
typedef short shortx8 __attribute__((ext_vector_type(8)));       // 8 bf16 bit-patterns (4 VGPRs)
typedef unsigned short ushortx8 __attribute__((ext_vector_type(8)));
typedef float floatx4 __attribute__((ext_vector_type(4)));

#define M_DIM 8192
#define N_DIM 4096
#define K_DIM 4096

// async global->LDS, 16B per lane. LDS dest is wave-uniform base + lane*16.
__device__ __forceinline__ void gld_lds16(const ushort_t* g, ushort_t* l) {
  __builtin_amdgcn_global_load_lds(
      (const __attribute__((address_space(1))) unsigned int*)g,
      (__attribute__((address_space(3))) unsigned int*)l,
      16, 0, 0);
}

// sign(v) as bf16 bits: +1 -> 0x3F80, -1 -> 0xBF80, 0/-0 -> 0
__device__ __forceinline__ ushort_t sgn_bf16(float v) {
  unsigned u = __float_as_uint(v);
  return (v == 0.0f) ? (ushort_t)0 : (ushort_t)(0x3F80u | ((u >> 16) & 0x8000u));
}

__global__ __launch_bounds__(256) void pack_x_kernel(const float* __restrict__ x,
                                                     ushort_t* __restrict__ xb,
                                                     double* __restrict__ accd) {
  const int t = threadIdx.x;
  const int lane = t & 63;
  const int w = t >> 6;
  size_t tid = (size_t)blockIdx.x * blockDim.x + t;
  size_t stride = (size_t)gridDim.x * blockDim.x;
  const size_t nchunk = (size_t)M_DIM * K_DIM / 8;   // 8 floats per chunk
  float s = 0.0f;
  for (size_t c = tid; c < nchunk; c += stride) {
    const float4* p = (const float4*)(x + c * 8);
    float4 v0 = p[0];
    float4 v1 = p[1];
    ushortx8 u;
    u[0] = sgn_bf16(v0.x); u[1] = sgn_bf16(v0.y); u[2] = sgn_bf16(v0.z); u[3] = sgn_bf16(v0.w);
    u[4] = sgn_bf16(v1.x); u[5] = sgn_bf16(v1.y); u[6] = sgn_bf16(v1.z); u[7] = sgn_bf16(v1.w);
    *(ushortx8*)(xb + c * 8) = u;
    s += fabsf(v0.x) + fabsf(v0.y) + fabsf(v0.z) + fabsf(v0.w)
       + fabsf(v1.x) + fabsf(v1.y) + fabsf(v1.z) + fabsf(v1.w);
  }
  #pragma unroll
  for (int off = 32; off > 0; off >>= 1) s += __shfl_down(s, off);
  __shared__ float part[4];
  if (lane == 0) part[w] = s;
  __syncthreads();
  if (t == 0) atomicAdd(accd, (double)(part[0] + part[1] + part[2] + part[3]));
}

__global__ __launch_bounds__(256) void pack_w_kernel(const float* __restrict__ Wm,
                                                     ushort_t* __restrict__ wb) {
  size_t tid = (size_t)blockIdx.x * blockDim.x + threadIdx.x;
  size_t stride = (size_t)gridDim.x * blockDim.x;
  const size_t nchunk = (size_t)N_DIM * K_DIM / 8;
  for (size_t c = tid; c < nchunk; c += stride) {
    const float4* p = (const float4*)(Wm + c * 8);
    float4 v0 = p[0];
    float4 v1 = p[1];
    ushortx8 u;
    u[0] = sgn_bf16(v0.x); u[1] = sgn_bf16(v0.y); u[2] = sgn_bf16(v0.z); u[3] = sgn_bf16(v0.w);
    u[4] = sgn_bf16(v1.x); u[5] = sgn_bf16(v1.y); u[6] = sgn_bf16(v1.z); u[7] = sgn_bf16(v1.w);
    *(ushortx8*)(wb + c * 8) = u;
  }
}

// C = Xb (M x K) * Wb^T (N x K) -> out[m][n] = (dot + bias[n]) * scale
// 128x128 C tile per block (4 waves, each 64x64 = 4x4 MFMA 16x16x32 subtiles), BK=64.
// LDS layout: row-major 128 rows x 64 bf16 (128 B/row). 16B chunk slot c of row r holds
// GLOBAL k-chunk (c + r) & 7  (XOR-ish swizzle to spread ds_read_b128 banks; write side is
// forced lane-linear by global_load_lds so the swizzle is applied to the global source).
__global__ __launch_bounds__(256) void gemm_kernel(const ushort_t* __restrict__ Xb,
                                                   const ushort_t* __restrict__ Wb,
                                                   const float* __restrict__ bias,
                                                   const double* __restrict__ accd,
                                                   float* __restrict__ out) {
  __shared__ __align__(16) ushort_t ldsA[128 * 64];
  __shared__ __align__(16) ushort_t ldsB[128 * 64];
  const int t = threadIdx.x;
  const int lane = t & 63;
  const int w = t >> 6;            // wave 0..3
  const int m16 = lane & 15;
  const int quad = lane >> 4;      // 0..3
  const int bM = blockIdx.y * 128;
  const int bN = blockIdx.x * 128;
  const int waveM = (w & 1) * 64;
  const int waveN = (w >> 1) * 64;
  const int srow = t >> 3;         // staging: 0..31 (row within 32-row round)
  const int schunk = t & 7;        // staging: 16B chunk slot 0..7

  floatx4 acc[4][4];
  #pragma unroll
  for (int i = 0; i < 4; ++i)
    #pragma unroll
    for (int j = 0; j < 4; ++j)
      acc[i][j] = (floatx4){0.0f, 0.0f, 0.0f, 0.0f};

  for (int kt = 0; kt < K_DIM; kt += 64) {
    __syncthreads();               // previous iteration's ds_reads done before overwrite
    #pragma unroll
    for (int i = 0; i < 4; ++i) {
      const int r = srow + 32 * i;           // local row 0..127
      const int g = (schunk + r) & 7;        // global chunk for this LDS slot
      // LDS dest: wave-uniform base (i,w uniform); HW adds lane*16 -> exactly slot (r, schunk)
      gld_lds16(Xb + (size_t)(bM + r) * K_DIM + kt + g * 8,
                ldsA + (size_t)(32 * i + 8 * w) * 64);
      gld_lds16(Wb + (size_t)(bN + r) * K_DIM + kt + g * 8,
                ldsB + (size_t)(32 * i + 8 * w) * 64);
    }
    __syncthreads();               // staging (vmcnt) drained by compiler before barrier

    #pragma unroll
    for (int s = 0; s < 2; ++s) {  // two k-steps of 32 within BK=64
      shortx8 a[4], b[4];
      #pragma unroll
      for (int i = 0; i < 4; ++i) {
        const int r = waveM + i * 16 + m16;          // A row (fragment layout m=lane&15)
        const int c = ((s * 4 + quad) - r) & 7;      // slot holding global chunk s*4+quad
        a[i] = *(const shortx8*)&ldsA[r * 64 + c * 8];
      }
      #pragma unroll
      for (int j = 0; j < 4; ++j) {
        const int r = waveN + j * 16 + m16;          // B row = output col (n=lane&15)
        const int c = ((s * 4 + quad) - r) & 7;
        b[j] = *(const shortx8*)&ldsB[r * 64 + c * 8];
      }
      #pragma unroll
      for (int i = 0; i < 4; ++i)
        #pragma unroll
        for (int j = 0; j < 4; ++j)
          acc[i][j] = __builtin_amdgcn_mfma_f32_16x16x32_bf16(a[i], b[j], acc[i][j], 0, 0, 0);
    }
  }

  const float scale = (float)(*accd * (1.0 / (double)((size_t)M_DIM * K_DIM)));

  // C/D layout: col = lane&15, row = quad*4 + reg  (HW-verified m89/m91)
  #pragma unroll
  for (int j = 0; j < 4; ++j) {
    const int col = bN + waveN + j * 16 + m16;
    const float bj = bias[col];
    #pragma unroll
    for (int i = 0; i < 4; ++i) {
      const size_t row0 = (size_t)(bM + waveM + i * 16 + quad * 4);
      float* po = out + row0 * N_DIM + col;
      #pragma unroll
      for (int r = 0; r < 4; ++r)
        po[(size_t)r * N_DIM] = (acc[i][j][r] + bj) * scale;
    }
  }
}

extern "C" void kernel_launch(void* const* d_in, const int* in_sizes, int n_in,
                              void* d_out, int out_size, void* d_ws, size_t ws_size,
                              hipStream_t stream) {
  const float* x = (const float*)d_in[0];   // [8192, 4096]
  const float* W = (const float*)d_in[1];   // [4096, 4096]
  const float* b = (const float*)d_in[2];   // [4096]
  float* out = (float*)d_out;               // [8192, 4096]

  double* accd = (double*)d_ws;                                   // 8B |x| sum
  ushort_t* Xb = (ushort_t*)((char*)d_ws + 256);                  // 64 MiB sign(x) bf16
  ushort_t* Wb = (ushort_t*)((char*)d_ws + 256 + (size_t)M_DIM * K_DIM * 2); // 32 MiB

  hipMemsetAsync(d_ws, 0, 8, stream);   // zero the reduction accumulator (ws is poisoned)
  pack_x_kernel<<<4096, 256, 0, stream>>>(x, Xb, accd);
  pack_w_kernel<<<2048, 256, 0, stream>>>(W, Wb);
  gemm_kernel<<<dim3(N_DIM / 128, M_DIM / 128), 256, 0, stream>>>(Xb, Wb, b, accd, out);
}

// Round 2
// 428.082 us; speedup vs baseline: 1.4234x; 1.4234x over previous
//
#include <hip/hip_runtime.h>

typedef int intx4 __attribute__((ext_vector_type(4)));

#define M_DIM 8192
#define N_DIM 4096
#define K_DIM 4096

// async global->LDS, 16B per lane. LDS dest is wave-uniform base + lane*16.
__device__ __forceinline__ void gld_lds16(const char* g, char* l) {
  __builtin_amdgcn_global_load_lds(
      (const __attribute__((address_space(1))) unsigned int*)g,
      (__attribute__((address_space(3))) unsigned int*)l,
      16, 0, 0);
}

// sign as i8: +1 / -1 / 0
__device__ __forceinline__ unsigned sgn_byte(float v) {
  return (unsigned)(unsigned char)(char)((v > 0.0f) - (v < 0.0f));
}

// pack 16 floats -> 16 sign bytes (one int4 store), accumulate |x|
__device__ __forceinline__ float pack16(const float* src, int* dst) {
  float s = 0.0f;
  int4 o;
  int* op = (int*)&o;
  #pragma unroll
  for (int q = 0; q < 4; ++q) {
    float4 v = ((const float4*)src)[q];
    op[q] = (int)(sgn_byte(v.x) | (sgn_byte(v.y) << 8) |
                  (sgn_byte(v.z) << 16) | (sgn_byte(v.w) << 24));
    s += fabsf(v.x) + fabsf(v.y) + fabsf(v.z) + fabsf(v.w);
  }
  *(int4*)dst = o;
  return s;
}

__global__ __launch_bounds__(256) void pack_x_kernel(const float* __restrict__ x,
                                                     char* __restrict__ xb,
                                                     double* __restrict__ accd) {
  const int t = threadIdx.x;
  const int lane = t & 63;
  const int w = t >> 6;
  size_t tid = (size_t)blockIdx.x * blockDim.x + t;
  size_t stride = (size_t)gridDim.x * blockDim.x;
  const size_t nchunk = (size_t)M_DIM * K_DIM / 16;   // 16 floats per chunk
  float s = 0.0f;
  for (size_t c = tid; c < nchunk; c += stride)
    s += pack16(x + c * 16, (int*)(xb + c * 16));
  #pragma unroll
  for (int off = 32; off > 0; off >>= 1) s += __shfl_down(s, off);
  __shared__ float part[4];
  if (lane == 0) part[w] = s;
  __syncthreads();
  if (t == 0) atomicAdd(accd, (double)(part[0] + part[1] + part[2] + part[3]));
}

__global__ __launch_bounds__(256) void pack_w_kernel(const float* __restrict__ Wm,
                                                     char* __restrict__ wb) {
  size_t tid = (size_t)blockIdx.x * blockDim.x + threadIdx.x;
  size_t stride = (size_t)gridDim.x * blockDim.x;
  const size_t nchunk = (size_t)N_DIM * K_DIM / 16;
  for (size_t c = tid; c < nchunk; c += stride) {
    const float* src = Wm + c * 16;
    int* dst = (int*)(wb + c * 16);
    int4 o;
    int* op = (int*)&o;
    #pragma unroll
    for (int q = 0; q < 4; ++q) {
      float4 v = ((const float4*)src)[q];
      op[q] = (int)(sgn_byte(v.x) | (sgn_byte(v.y) << 8) |
                    (sgn_byte(v.z) << 16) | (sgn_byte(v.w) << 24));
    }
    *(int4*)dst = o;
  }
}

// C = Xb (M x K, i8) * Wb^T (N x K, i8); out[m][n] = ((float)dot + bias[n]) * scale
// 128x128 C tile per block (4 waves, each 64x64 = 4x4 MFMA 16x16x64 subtiles), BK=128.
// LDS: row-major 128 rows x 128 B. 16B chunk slot c of row r holds GLOBAL k-chunk (c+r)&7
// (swizzle applied on the global source; global_load_lds forces lane-linear LDS dests).
// Byte layout identical to the verified bf16 R1 kernel -> 0 bank conflicts carry over.
__global__ __launch_bounds__(256) void gemm_kernel(const char* __restrict__ Xb,
                                                   const char* __restrict__ Wb,
                                                   const float* __restrict__ bias,
                                                   const double* __restrict__ accd,
                                                   float* __restrict__ out) {
  __shared__ __align__(16) char ldsA[128 * 128];
  __shared__ __align__(16) char ldsB[128 * 128];
  const int t = threadIdx.x;
  const int lane = t & 63;
  const int w = t >> 6;            // wave 0..3
  const int m16 = lane & 15;
  const int quad = lane >> 4;      // 0..3
  const int bM = blockIdx.y * 128;
  const int bN = blockIdx.x * 128;
  const int waveM = (w & 1) * 64;
  const int waveN = (w >> 1) * 64;
  const int srow = t >> 3;         // staging row within 32-row round
  const int schunk = t & 7;        // staging 16B chunk slot 0..7

  intx4 acc[4][4];
  #pragma unroll
  for (int i = 0; i < 4; ++i)
    #pragma unroll
    for (int j = 0; j < 4; ++j)
      acc[i][j] = (intx4){0, 0, 0, 0};

  for (int kt = 0; kt < K_DIM; kt += 128) {
    __syncthreads();               // previous iteration's ds_reads done before overwrite
    #pragma unroll
    for (int i = 0; i < 4; ++i) {
      const int r = srow + 32 * i;           // local row 0..127
      const int g = (schunk + r) & 7;        // global 16B-chunk for this LDS slot
      gld_lds16(Xb + (size_t)(bM + r) * K_DIM + kt + g * 16,
                ldsA + (size_t)(32 * i + 8 * w) * 128);
      gld_lds16(Wb + (size_t)(bN + r) * K_DIM + kt + g * 16,
                ldsB + (size_t)(32 * i + 8 * w) * 128);
    }
    __syncthreads();

    #pragma unroll
    for (int s = 0; s < 2; ++s) {  // two k-steps of 64 within BK=128
      intx4 a[4], b[4];
      #pragma unroll
      for (int i = 0; i < 4; ++i) {
        const int r = waveM + i * 16 + m16;          // A row (m = lane&15)
        const int c = ((s * 4 + quad) - r) & 7;      // slot holding global chunk s*4+quad
        a[i] = *(const intx4*)&ldsA[r * 128 + c * 16];
      }
      #pragma unroll
      for (int j = 0; j < 4; ++j) {
        const int r = waveN + j * 16 + m16;          // B row = output col
        const int c = ((s * 4 + quad) - r) & 7;
        b[j] = *(const intx4*)&ldsB[r * 128 + c * 16];
      }
      #pragma unroll
      for (int i = 0; i < 4; ++i)
        #pragma unroll
        for (int j = 0; j < 4; ++j)
          acc[i][j] = __builtin_amdgcn_mfma_i32_16x16x64_i8(a[i], b[j], acc[i][j], 0, 0, 0);
    }
  }

  const float scale = (float)(*accd * (1.0 / (double)((size_t)M_DIM * K_DIM)));

  // C/D layout (shape-determined, dtype-independent): col = lane&15, row = quad*4 + reg
  #pragma unroll
  for (int j = 0; j < 4; ++j) {
    const int col = bN + waveN + j * 16 + m16;
    const float bj = bias[col];
    #pragma unroll
    for (int i = 0; i < 4; ++i) {
      const size_t row0 = (size_t)(bM + waveM + i * 16 + quad * 4);
      float* po = out + row0 * N_DIM + col;
      #pragma unroll
      for (int r = 0; r < 4; ++r)
        po[(size_t)r * N_DIM] = ((float)acc[i][j][r] + bj) * scale;
    }
  }
}

extern "C" void kernel_launch(void* const* d_in, const int* in_sizes, int n_in,
                              void* d_out, int out_size, void* d_ws, size_t ws_size,
                              hipStream_t stream) {
  const float* x = (const float*)d_in[0];   // [8192, 4096]
  const float* W = (const float*)d_in[1];   // [4096, 4096]
  const float* b = (const float*)d_in[2];   // [4096]
  float* out = (float*)d_out;               // [8192, 4096]

  double* accd = (double*)d_ws;                                   // 8B |x| sum
  char* Xb = (char*)d_ws + 256;                                   // 32 MiB sign(x) i8
  char* Wb = (char*)d_ws + 256 + (size_t)M_DIM * K_DIM;           // 16 MiB sign(W) i8

  hipMemsetAsync(d_ws, 0, 8, stream);   // zero the reduction accumulator (ws is poisoned)
  pack_x_kernel<<<4096, 256, 0, stream>>>(x, Xb, accd);
  pack_w_kernel<<<2048, 256, 0, stream>>>(W, Wb);
  gemm_kernel<<<dim3(N_DIM / 128, M_DIM / 128), 256, 0, stream>>>(Xb, Wb, b, accd, out);
}

// Round 3
// 350.733 us; speedup vs baseline: 1.7373x; 1.2205x over previous
//
#include <hip/hip_runtime.h>

typedef int intx4 __attribute__((ext_vector_type(4)));
typedef int intx8 __attribute__((ext_vector_type(8)));
typedef float floatx4 __attribute__((ext_vector_type(4)));

#define M_DIM 8192
#define N_DIM 4096
#define K_DIM 4096
#define KB2 (K_DIM / 2)   // bytes per packed fp4 row

// async global->LDS, 16B per lane. LDS dest is wave-uniform base + lane*16.
__device__ __forceinline__ void gld_lds16(const char* g, char* l) {
  __builtin_amdgcn_global_load_lds(
      (const __attribute__((address_space(1))) unsigned int*)g,
      (__attribute__((address_space(3))) unsigned int*)l,
      16, 0, 0);
}

// fp4 e2m1 sign nibble: +1 -> 0x2, -1 -> 0xA, 0 -> 0x0
__device__ __forceinline__ unsigned nib(float v) {
  return v > 0.0f ? 0x2u : (v < 0.0f ? 0xAu : 0x0u);
}

// pack 32 floats -> 16 fp4-pair bytes (one int4 store); returns abs-sum
// nibble order: element 2b -> bits[3:0] of byte b (low nibble first)
__device__ __forceinline__ float pack32(const float* __restrict__ src, int4* __restrict__ dst) {
  float s = 0.0f;
  int4 o;
  int* op = (int*)&o;
  #pragma unroll
  for (int q = 0; q < 4; ++q) {
    float4 v0 = ((const float4*)src)[2 * q];
    float4 v1 = ((const float4*)src)[2 * q + 1];
    op[q] = (int)(nib(v0.x) | (nib(v0.y) << 4) | (nib(v0.z) << 8) | (nib(v0.w) << 12) |
                  (nib(v1.x) << 16) | (nib(v1.y) << 20) | (nib(v1.z) << 24) | (nib(v1.w) << 28));
    s += fabsf(v0.x) + fabsf(v0.y) + fabsf(v0.z) + fabsf(v0.w)
       + fabsf(v1.x) + fabsf(v1.y) + fabsf(v1.z) + fabsf(v1.w);
  }
  *dst = o;
  return s;
}

// Fused pack: blocks [0,2048) pack x (+ |x| reduction), blocks [2048,3072) pack W.
__global__ __launch_bounds__(256) void pack_kernel(const float* __restrict__ x,
                                                   const float* __restrict__ Wm,
                                                   char* __restrict__ xb,
                                                   char* __restrict__ wb,
                                                   double* __restrict__ accd) {
  const int t = threadIdx.x;
  if (blockIdx.x < 2048) {
    const size_t nch = (size_t)M_DIM * K_DIM / 32;
    size_t tid = (size_t)blockIdx.x * 256 + t;
    float s = 0.0f;
    for (size_t c = tid; c < nch; c += (size_t)2048 * 256)
      s += pack32(x + c * 32, (int4*)(xb + c * 16));
    #pragma unroll
    for (int off = 32; off > 0; off >>= 1) s += __shfl_down(s, off);
    __shared__ float part[4];
    if ((t & 63) == 0) part[t >> 6] = s;
    __syncthreads();
    if (t == 0) atomicAdd(accd, (double)(part[0] + part[1] + part[2] + part[3]));
  } else {
    const size_t nch = (size_t)N_DIM * K_DIM / 32;
    size_t tid = (size_t)(blockIdx.x - 2048) * 256 + t;
    for (size_t c = tid; c < nch; c += (size_t)1024 * 256)
      pack32(Wm + c * 32, (int4*)(wb + c * 16));
  }
}

// C = Xb (M x K, fp4) * Wb^T (N x K, fp4); out[m][n] = (dot + bias[n]) * scale
// 128x128 C tile / 4 waves / 4x4 subtiles of 16x16, BK=128 via mfma_scale 16x16x128 fp4
// with unit scales (0x7F e8m0). Dot products are exact integers in fp32 acc.
//
// LDS layout (per matrix, 8 KB): row pairs interleaved into 128-B lines:
//   addr(r, c) = (r>>1)*128 + c*32 + (r&1)*16,  c = 16B chunk slot 0..3
// slot c of row r holds GLOBAL k-chunk g = (c + (r>>1)) & 3  (swizzle so 8
// consecutive lanes of a b128 fragment read cover all 32 banks; write side is
// lane-linear by global_load_lds, so swizzle is applied on the global source).
__global__ __launch_bounds__(256) void gemm_kernel(const char* __restrict__ Xb,
                                                   const char* __restrict__ Wb,
                                                   const float* __restrict__ bias,
                                                   const double* __restrict__ accd,
                                                   float* __restrict__ out) {
  __shared__ __align__(16) char ldsA[128 * 64];
  __shared__ __align__(16) char ldsB[128 * 64];
  const int t = threadIdx.x;
  const int lane = t & 63;
  const int w = t >> 6;            // wave 0..3
  const int m16 = lane & 15;
  const int quad = lane >> 4;      // 0..3 -> k-chunk of 32 fp4 (16 B)
  const int bM = blockIdx.y * 128;
  const int bN = blockIdx.x * 128;
  const int waveM = (w & 1) * 64;
  const int waveN = (w >> 1) * 64;
  // staging coords: thread t covers row rl = 2*(t>>3)+(t&1), slot sc = (t>>1)&3
  // (so that LDS addr(rl,sc) == t*16, matching global_load_lds lane-linear dests)
  const int srl = 2 * (t >> 3) + (t & 1);   // 0..63 per round
  const int ssc = (t >> 1) & 3;

  floatx4 acc[4][4];
  #pragma unroll
  for (int i = 0; i < 4; ++i)
    #pragma unroll
    for (int j = 0; j < 4; ++j)
      acc[i][j] = (floatx4){0.0f, 0.0f, 0.0f, 0.0f};

  for (int kt = 0; kt < K_DIM; kt += 128) {
    __syncthreads();               // previous iteration's ds_reads done before overwrite
    #pragma unroll
    for (int rd = 0; rd < 2; ++rd) {
      const int r = rd * 64 + srl;                 // local row 0..127
      const int g = (ssc + (r >> 1)) & 3;          // global 16B chunk for this slot
      const size_t goff = (size_t)(kt >> 1) + g * 16;
      gld_lds16(Xb + (size_t)(bM + r) * KB2 + goff, ldsA + rd * 4096 + w * 1024);
      gld_lds16(Wb + (size_t)(bN + r) * KB2 + goff, ldsB + rd * 4096 + w * 1024);
    }
    __syncthreads();

    intx8 a8[4];
    #pragma unroll
    for (int i = 0; i < 4; ++i) {
      const int m = waveM + i * 16 + m16;          // A row (m = lane&15)
      const int c = (quad - (m >> 1)) & 3;         // slot holding global chunk `quad`
      intx4 lo = *(const intx4*)&ldsA[(m >> 1) * 128 + c * 32 + (m & 1) * 16];
      a8[i] = (intx8){lo[0], lo[1], lo[2], lo[3], 0, 0, 0, 0};   // fp4 uses low 4 regs
    }
    #pragma unroll
    for (int j = 0; j < 4; ++j) {
      const int n = waveN + j * 16 + m16;          // B row = output col
      const int c = (quad - (n >> 1)) & 3;
      intx4 lo = *(const intx4*)&ldsB[(n >> 1) * 128 + c * 32 + (n & 1) * 16];
      intx8 b8 = (intx8){lo[0], lo[1], lo[2], lo[3], 0, 0, 0, 0};
      #pragma unroll
      for (int i = 0; i < 4; ++i)
        acc[i][j] = __builtin_amdgcn_mfma_scale_f32_16x16x128_f8f6f4(
            a8[i], b8, acc[i][j],
            4, 4,                       // cbsz=fp4(e2m1), blgp=fp4(e2m1)
            0, 0x7F7F7F7F,              // scale_a opsel, scales = 1.0
            0, 0x7F7F7F7F);             // scale_b opsel, scales = 1.0
    }
  }

  const float scale = (float)(*accd * (1.0 / (double)((size_t)M_DIM * K_DIM)));

  // C/D layout (shape-determined, dtype-independent): col = lane&15, row = quad*4 + reg
  #pragma unroll
  for (int j = 0; j < 4; ++j) {
    const int col = bN + waveN + j * 16 + m16;
    const float bj = bias[col];
    #pragma unroll
    for (int i = 0; i < 4; ++i) {
      const size_t row0 = (size_t)(bM + waveM + i * 16 + quad * 4);
      float* po = out + row0 * N_DIM + col;
      #pragma unroll
      for (int r = 0; r < 4; ++r)
        po[(size_t)r * N_DIM] = (acc[i][j][r] + bj) * scale;
    }
  }
}

extern "C" void kernel_launch(void* const* d_in, const int* in_sizes, int n_in,
                              void* d_out, int out_size, void* d_ws, size_t ws_size,
                              hipStream_t stream) {
  const float* x = (const float*)d_in[0];   // [8192, 4096]
  const float* W = (const float*)d_in[1];   // [4096, 4096]
  const float* b = (const float*)d_in[2];   // [4096]
  float* out = (float*)d_out;               // [8192, 4096]

  double* accd = (double*)d_ws;                                   // 8B |x| sum
  char* Xb = (char*)d_ws + 256;                                   // 16 MiB sign(x) fp4
  char* Wb = (char*)d_ws + 256 + (size_t)M_DIM * K_DIM / 2;       // 8 MiB sign(W) fp4

  hipMemsetAsync(d_ws, 0, 8, stream);   // zero the reduction accumulator (ws is poisoned)
  pack_kernel<<<3072, 256, 0, stream>>>(x, W, Xb, Wb, accd);
  gemm_kernel<<<dim3(N_DIM / 128, M_DIM / 128), 256, 0, stream>>>(Xb, Wb, b, accd, out);
}